// Round 1
// baseline (131.514 us; speedup 1.0000x reference)
//
#include <hip/hip_runtime.h>
#include <hip/hip_bf16.h>

typedef __bf16 bf16_t;
typedef __bf16 bf16x4 __attribute__((ext_vector_type(4)));
typedef __bf16 bf16x8 __attribute__((ext_vector_type(8)));
typedef float f32x4 __attribute__((ext_vector_type(4)));

#define B_ 2
#define T_ 2048
#define C_ 1024
#define H_ 16
#define HD_ 64
#define RD_ 32
#define M_ (B_ * T_)  // 4096

// ---------------- convert x fp32 -> bf16 ----------------
__global__ __launch_bounds__(256) void k_cvt(const float* __restrict__ in,
                                             bf16_t* __restrict__ out, int n4) {
    int i = blockIdx.x * 256 + threadIdx.x;
    if (i >= n4) return;
    float4 v = reinterpret_cast<const float4*>(in)[i];
    bf16x4 o;
    o[0] = (bf16_t)v.x; o[1] = (bf16_t)v.y; o[2] = (bf16_t)v.z; o[3] = (bf16_t)v.w;
    reinterpret_cast<bf16x4*>(out)[i] = o;
}

// ---------------- transpose + convert W (NxN fp32 -> Wt[n][k] bf16) ----------------
__global__ __launch_bounds__(256) void k_transpose_cvt(const float* __restrict__ W,
                                                       bf16_t* __restrict__ Wt, int N) {
    __shared__ float tile[32][33];
    int n0 = blockIdx.x * 32, k0 = blockIdx.y * 32;
    int tx = threadIdx.x, ty = threadIdx.y;
    for (int i = ty; i < 32; i += 8)
        tile[i][tx] = W[(size_t)(k0 + i) * N + n0 + tx];
    __syncthreads();
    for (int i = ty; i < 32; i += 8)
        Wt[(size_t)(n0 + i) * N + k0 + tx] = (bf16_t)tile[tx][i];
}

// ---------------- GEMM: C[M][N] fp32 = A[M][K]bf16 * Bt[N][K]bf16^T ----------------
// m97 structure: 128x128 tile, BK=32, 4 waves (2x2), global_load_lds width 16.
__global__ __launch_bounds__(256) void k_gemm_bt(const bf16_t* __restrict__ A,
                                                 const bf16_t* __restrict__ Bt,
                                                 float* __restrict__ C,
                                                 int M, int N, int K) {
    __shared__ bf16_t As[128 * 32];
    __shared__ bf16_t Bs[128 * 32];
    const int tid = threadIdx.x;
    const int lane = tid & 63, w = tid >> 6;
    const int wr = w >> 1, wc = w & 1;
    const int g = lane >> 4, li = lane & 15;
    const size_t rowA0 = (size_t)blockIdx.y * 128;
    const size_t colB0 = (size_t)blockIdx.x * 128;
    const bf16_t* Ab = A + rowA0 * K;
    const bf16_t* Bb = Bt + colB0 * K;
    f32x4 acc[4][4] = {};
    const int lrow = lane >> 2;       // 0..15 within a 16-row wave chunk
    const int lc8 = (lane & 3) * 8;   // element offset (16B chunks)

    for (int k0 = 0; k0 < K; k0 += 32) {
        __syncthreads();  // prior-iter LDS reads done before overwrite
#pragma unroll
        for (int half = 0; half < 2; ++half) {
            const int rbase = half * 64 + w * 16;
            const bf16_t* srcA = Ab + (size_t)(rbase + lrow) * K + k0 + lc8;
            const bf16_t* srcB = Bb + (size_t)(rbase + lrow) * K + k0 + lc8;
            __builtin_amdgcn_global_load_lds(
                (const __attribute__((address_space(1))) void*)srcA,
                (__attribute__((address_space(3))) void*)(As + rbase * 32), 16, 0, 0);
            __builtin_amdgcn_global_load_lds(
                (const __attribute__((address_space(1))) void*)srcB,
                (__attribute__((address_space(3))) void*)(Bs + rbase * 32), 16, 0, 0);
        }
        __syncthreads();  // drains vmcnt: staged data visible
        bf16x8 af[4], bfv[4];
#pragma unroll
        for (int i = 0; i < 4; ++i) {
            af[i]  = *reinterpret_cast<const bf16x8*>(As + (wr * 64 + i * 16 + li) * 32 + g * 8);
            bfv[i] = *reinterpret_cast<const bf16x8*>(Bs + (wc * 64 + i * 16 + li) * 32 + g * 8);
        }
#pragma unroll
        for (int i = 0; i < 4; ++i)
#pragma unroll
            for (int j = 0; j < 4; ++j)
                acc[i][j] = __builtin_amdgcn_mfma_f32_16x16x32_bf16(af[i], bfv[j], acc[i][j], 0, 0, 0);
    }
#pragma unroll
    for (int i = 0; i < 4; ++i)
#pragma unroll
        for (int j = 0; j < 4; ++j)
#pragma unroll
            for (int r = 0; r < 4; ++r) {
                size_t row = rowA0 + wr * 64 + i * 16 + g * 4 + r;
                size_t col = colB0 + wc * 64 + j * 16 + li;
                C[row * N + col] = acc[i][j][r];
            }
}

// ---------------- fused RoPE + RMS-norm; writes Q in (B,H,T,64) bf16 ----------------
__global__ __launch_bounds__(256) void k_rope_rms(const float* __restrict__ w32,
                                                  const float* __restrict__ ct,
                                                  const float* __restrict__ st,
                                                  bf16_t* __restrict__ q) {
    const int tid = threadIdx.x;
    const int lane = tid & 63;
    const int row = blockIdx.x * 4 + (tid >> 6);  // row in [0, B*T*H)
    const int h = row & (H_ - 1);
    const int t = (row >> 4) & (T_ - 1);
    const int b = row >> 15;
    float v = w32[(size_t)row * 64 + lane];
    float p = __shfl_xor(v, 32);
    const int dr = lane & 31;
    float c = ct[t * RD_ + dr];
    float s = st[t * RD_ + dr];
    // lane<32: y1 = x1*c + x2*s ; lane>=32: y2 = -x1*s + x2*c
    float y = (lane < 32) ? (v * c + p * s) : (v * c - p * s);
    float sq = y * y;
#pragma unroll
    for (int off = 1; off < 64; off <<= 1) sq += __shfl_xor(sq, off);
    float rn = rsqrtf(sq * (1.0f / 64.0f) + 1.1920929e-7f);
    q[(((size_t)b * H_ + h) * T_ + t) * 64 + lane] = (bf16_t)(y * rn);
}

// ---------------- flash attention, sliding window; Q=K=V tensor ----------------
// grid (T/64, H, B), 256 threads. Wave w handles 16 q-rows. Online softmax.
__global__ __launch_bounds__(256) void k_attn(const bf16_t* __restrict__ qkv,
                                              bf16_t* __restrict__ aout,
                                              const int* __restrict__ wlp) {
    __shared__ bf16_t kv[64][72];      // [j][d] (pad to 72 to break bank conflicts)
    __shared__ bf16_t vt[64][72];      // [d][j]
    __shared__ bf16_t pb[4][16][72];   // per-wave P [q][j]
    const int tid = threadIdx.x;
    const int lane = tid & 63, w = tid >> 6;
    const int g = lane >> 4, li = lane & 15;
    const int Q0 = blockIdx.x * 64;
    const int h = blockIdx.y, b = blockIdx.z;
    const bf16_t* base = qkv + ((size_t)(b * H_ + h) * T_) * 64;

    const int wl = wlp[0];
    const int wle = (wl <= 0 || wl > T_) ? T_ : wl;

    const int qw = Q0 + w * 16;
    bf16x8 aq[2];
    aq[0] = *reinterpret_cast<const bf16x8*>(base + (size_t)(qw + li) * 64 + g * 8);
    aq[1] = *reinterpret_cast<const bf16x8*>(base + (size_t)(qw + li) * 64 + 32 + g * 8);

    f32x4 o[4] = {};
    float m[4], l[4];
#pragma unroll
    for (int r = 0; r < 4; ++r) { m[r] = -1e30f; l[r] = 0.f; }

    const int kb0 = (Q0 > wle) ? ((Q0 - wle) >> 6) : 0;
    const int kb1 = Q0 >> 6;

    for (int kb = kb0; kb <= kb1; ++kb) {
        const int J0 = kb * 64;
        __syncthreads();  // prior-iter LDS reads done
#pragma unroll
        for (int rr = 0; rr < 2; ++rr) {
            int cch = tid + rr * 256;
            int row = cch >> 3;
            int c8 = (cch & 7) * 8;
            bf16x8 v = *reinterpret_cast<const bf16x8*>(base + (size_t)(J0 + row) * 64 + c8);
            bf16x4 lo, hi;
#pragma unroll
            for (int e = 0; e < 4; ++e) { lo[e] = v[e]; hi[e] = v[e + 4]; }
            *reinterpret_cast<bf16x4*>(&kv[row][c8]) = lo;
            *reinterpret_cast<bf16x4*>(&kv[row][c8 + 4]) = hi;
#pragma unroll
            for (int e = 0; e < 8; ++e) vt[c8 + e][row] = v[e];
        }
        __syncthreads();
        const bool active = (J0 <= qw + 15) && (J0 + 63 >= qw - wle);
        if (active) {
            f32x4 s4[4] = {};
#pragma unroll
            for (int ks = 0; ks < 2; ++ks) {
#pragma unroll
                for (int nb = 0; nb < 4; ++nb) {
                    const bf16_t* kp = &kv[nb * 16 + li][ks * 32 + g * 8];
                    bf16x4 b0 = *reinterpret_cast<const bf16x4*>(kp);
                    bf16x4 b1 = *reinterpret_cast<const bf16x4*>(kp + 4);
                    bf16x8 bk;
#pragma unroll
                    for (int e = 0; e < 4; ++e) { bk[e] = b0[e]; bk[e + 4] = b1[e]; }
                    s4[nb] = __builtin_amdgcn_mfma_f32_16x16x32_bf16(aq[ks], bk, s4[nb], 0, 0, 0);
                }
            }
            float sv[4][4], mn[4];
#pragma unroll
            for (int r = 0; r < 4; ++r) mn[r] = m[r];
#pragma unroll
            for (int nb = 0; nb < 4; ++nb) {
                const int jg = J0 + nb * 16 + li;
#pragma unroll
                for (int r = 0; r < 4; ++r) {
                    const int qg = qw + g * 4 + r;
                    const int dist = qg - jg;
                    float x = s4[nb][r] * 0.125f;  // HD^-0.5 = 1/8
                    sv[nb][r] = (dist >= 0 && dist <= wle) ? x : -__builtin_inff();
                    mn[r] = fmaxf(mn[r], sv[nb][r]);
                }
            }
#pragma unroll
            for (int off = 1; off < 16; off <<= 1)
#pragma unroll
                for (int r = 0; r < 4; ++r)
                    mn[r] = fmaxf(mn[r], __shfl_xor(mn[r], off));
            float al[4], ladd[4], pvv[4][4];
#pragma unroll
            for (int r = 0; r < 4; ++r) {
                al[r] = __expf(m[r] - mn[r]);
                m[r] = mn[r];
                ladd[r] = 0.f;
            }
#pragma unroll
            for (int nb = 0; nb < 4; ++nb)
#pragma unroll
                for (int r = 0; r < 4; ++r) {
                    float p = __expf(sv[nb][r] - m[r]);  // exp(-inf - finite) = 0
                    pvv[nb][r] = p;
                    ladd[r] += p;
                }
#pragma unroll
            for (int off = 1; off < 16; off <<= 1)
#pragma unroll
                for (int r = 0; r < 4; ++r)
                    ladd[r] += __shfl_xor(ladd[r], off);
#pragma unroll
            for (int r = 0; r < 4; ++r) l[r] = l[r] * al[r] + ladd[r];
#pragma unroll
            for (int dnb = 0; dnb < 4; ++dnb)
#pragma unroll
                for (int r = 0; r < 4; ++r) o[dnb][r] *= al[r];
            // P (C/D layout) -> LDS [q][j] so PV can read A-frags contiguous in j
#pragma unroll
            for (int nb = 0; nb < 4; ++nb)
#pragma unroll
                for (int r = 0; r < 4; ++r)
                    pb[w][g * 4 + r][nb * 16 + li] = (bf16_t)pvv[nb][r];
#pragma unroll
            for (int ks = 0; ks < 2; ++ks) {
                const bf16_t* pp = &pb[w][li][ks * 32 + g * 8];
                bf16x4 p0 = *reinterpret_cast<const bf16x4*>(pp);
                bf16x4 p1 = *reinterpret_cast<const bf16x4*>(pp + 4);
                bf16x8 pa;
#pragma unroll
                for (int e = 0; e < 4; ++e) { pa[e] = p0[e]; pa[e + 4] = p1[e]; }
#pragma unroll
                for (int dnb = 0; dnb < 4; ++dnb) {
                    const bf16_t* vp = &vt[dnb * 16 + li][ks * 32 + g * 8];
                    bf16x4 v0 = *reinterpret_cast<const bf16x4*>(vp);
                    bf16x4 v1 = *reinterpret_cast<const bf16x4*>(vp + 4);
                    bf16x8 bv;
#pragma unroll
                    for (int e = 0; e < 4; ++e) { bv[e] = v0[e]; bv[e + 4] = v1[e]; }
                    o[dnb] = __builtin_amdgcn_mfma_f32_16x16x32_bf16(pa, bv, o[dnb], 0, 0, 0);
                }
            }
        }
    }
    float rl[4];
#pragma unroll
    for (int r = 0; r < 4; ++r) rl[r] = (l[r] > 0.f) ? (1.0f / l[r]) : 0.f;
#pragma unroll
    for (int dnb = 0; dnb < 4; ++dnb)
#pragma unroll
        for (int r = 0; r < 4; ++r) {
            size_t t = (size_t)qw + g * 4 + r;
            aout[((size_t)b * T_ + t) * C_ + h * 64 + dnb * 16 + li] =
                (bf16_t)(o[dnb][r] * rl[r]);
        }
}

extern "C" void kernel_launch(void* const* d_in, const int* in_sizes, int n_in,
                              void* d_out, int out_size, void* d_ws, size_t ws_size,
                              hipStream_t stream) {
    const float* x     = (const float*)d_in[0];
    const float* ct    = (const float*)d_in[1];
    const float* st    = (const float*)d_in[2];
    const float* Wqkv  = (const float*)d_in[3];
    const float* Wproj = (const float*)d_in[4];
    const int*   wl    = (const int*)d_in[5];
    float* out = (float*)d_out;
    char* ws = (char*)d_ws;

    bf16_t* xb    = (bf16_t*)(ws);                       // 8 MB  x in bf16
    bf16_t* wqkvt = (bf16_t*)(ws + (8ull << 20));        // 2 MB  W_qkv^T bf16
    bf16_t* wprot = (bf16_t*)(ws + (10ull << 20));       // 2 MB  W_proj^T bf16
    float*  w32   = (float*) (ws + (12ull << 20));       // 16 MB qkv GEMM out fp32
    bf16_t* q     = (bf16_t*)(ws + (28ull << 20));       // 8 MB  rope+rms out (B,H,T,64)
    bf16_t* ao    = (bf16_t*)(ws + (36ull << 20));       // 8 MB  attn out (B,T,C)

    k_cvt<<<dim3((M_ * C_ / 4 + 255) / 256), dim3(256), 0, stream>>>(x, xb, M_ * C_ / 4);
    k_transpose_cvt<<<dim3(32, 32), dim3(32, 8), 0, stream>>>(Wqkv, wqkvt, C_);
    k_transpose_cvt<<<dim3(32, 32), dim3(32, 8), 0, stream>>>(Wproj, wprot, C_);
    k_gemm_bt<<<dim3(C_ / 128, M_ / 128), dim3(256), 0, stream>>>(xb, wqkvt, w32, M_, C_, C_);
    k_rope_rms<<<dim3(M_ * H_ / 4), dim3(256), 0, stream>>>(w32, ct, st, q);
    k_attn<<<dim3(T_ / 64, H_, B_), dim3(256), 0, stream>>>(q, ao, wl);
    k_gemm_bt<<<dim3(C_ / 128, M_ / 128), dim3(256), 0, stream>>>(ao, wprot, out, M_, C_, C_);
}